// Round 1
// baseline (2048.879 us; speedup 1.0000x reference)
//
#include <hip/hip_runtime.h>
#include <math.h>

#define S_LEN 2048
#define NH 16
#define HDIM 64
#define BATCH 2
#define BHC 32          // BATCH*NH
#define KK 409          // int(2048 * (1.0 - 0.8)) per reference float math
#define DMODEL 1024
#define MROWS 4096      // BATCH*S_LEN

__device__ __forceinline__ unsigned f2ord(float f) {
    unsigned u = __float_as_uint(f);
    return (u & 0x80000000u) ? ~u : (u | 0x80000000u);
}

// ---------------------------------------------------------------------------
// C = A @ W^T + bias.  A: [4096,1024] row-major, W: [N=1024, K=1024] row-major.
// headsplit==1: write out[b,h,s,hd]  (n = h*64+hd, m = b*2048+s)
// headsplit==0: write out[m,n] plain row-major
// Tile: 128(M) x 64(N), BK=16, 256 threads, 8x4 micro-tile per thread.
// ---------------------------------------------------------------------------
__global__ __launch_bounds__(256)
void gemm_nt(const float* __restrict__ A, const float* __restrict__ W,
             const float* __restrict__ bias, float* __restrict__ out,
             int headsplit)
{
    __shared__ __align__(16) float As[16][132];  // [k][m], pad keeps 16B align
    __shared__ __align__(16) float Ws[16][68];   // [k][n]
    const int tid = threadIdx.x;
    const int n0 = blockIdx.x * 64;
    const int m0 = blockIdx.y * 128;
    const int tx = tid & 15;   // 4 cols each
    const int ty = tid >> 4;   // 8 rows each

    float acc[8][4];
#pragma unroll
    for (int i = 0; i < 8; ++i)
#pragma unroll
        for (int j = 0; j < 4; ++j) acc[i][j] = 0.f;

    const int arow = tid >> 2;          // 0..63
    const int akq  = (tid & 3) * 4;     // k quad offset

    for (int k0 = 0; k0 < 1024; k0 += 16) {
        const float4 av0 = *(const float4*)(A + (size_t)(m0 + arow) * 1024 + k0 + akq);
        const float4 av1 = *(const float4*)(A + (size_t)(m0 + arow + 64) * 1024 + k0 + akq);
        const float4 wv  = *(const float4*)(W + (size_t)(n0 + arow) * 1024 + k0 + akq);
        __syncthreads();   // WAR: previous iteration's compute reads done
        As[akq + 0][arow] = av0.x; As[akq + 1][arow] = av0.y;
        As[akq + 2][arow] = av0.z; As[akq + 3][arow] = av0.w;
        As[akq + 0][arow + 64] = av1.x; As[akq + 1][arow + 64] = av1.y;
        As[akq + 2][arow + 64] = av1.z; As[akq + 3][arow + 64] = av1.w;
        Ws[akq + 0][arow] = wv.x; Ws[akq + 1][arow] = wv.y;
        Ws[akq + 2][arow] = wv.z; Ws[akq + 3][arow] = wv.w;
        __syncthreads();   // RAW: tiles visible
#pragma unroll
        for (int kk = 0; kk < 16; ++kk) {
            const float4 a0 = *(const float4*)&As[kk][ty * 8];
            const float4 a1 = *(const float4*)&As[kk][ty * 8 + 4];
            const float4 bv = *(const float4*)&Ws[kk][tx * 4];
            const float a[8] = {a0.x, a0.y, a0.z, a0.w, a1.x, a1.y, a1.z, a1.w};
            const float b[4] = {bv.x, bv.y, bv.z, bv.w};
#pragma unroll
            for (int i = 0; i < 8; ++i)
#pragma unroll
                for (int j = 0; j < 4; ++j) acc[i][j] += a[i] * b[j];
        }
    }

    const int nb = n0 + tx * 4;
    const float4 b4 = *(const float4*)(bias + nb);
#pragma unroll
    for (int i = 0; i < 8; ++i) {
        const int m = m0 + ty * 8 + i;
        float4 o;
        o.x = acc[i][0] + b4.x; o.y = acc[i][1] + b4.y;
        o.z = acc[i][2] + b4.z; o.w = acc[i][3] + b4.w;
        if (headsplit) {
            const int b = m >> 11, s = m & 2047;
            const int h = nb >> 6, hd = nb & 63;
            *(float4*)(out + ((size_t)((b * NH + h) * S_LEN + s)) * HDIM + hd) = o;
        } else {
            *(float4*)(out + (size_t)m * 1024 + nb) = o;
        }
    }
}

// ---------------------------------------------------------------------------
// K[bh,s,hd] -> Kt[bh,hd,s]
// ---------------------------------------------------------------------------
__global__ __launch_bounds__(256)
void transpose_k(const float* __restrict__ K, float* __restrict__ Kt)
{
    __shared__ float t[64][65];
    const int tid = threadIdx.x;
    const int s0 = blockIdx.x * 64;
    const int bh = blockIdx.y;
    const float* Kb = K + (size_t)bh * S_LEN * HDIM;
#pragma unroll
    for (int i = 0; i < 4; ++i) {
        const int f = tid + i * 256;
        const int s = f >> 4;
        const int hq = (f & 15) * 4;
        const float4 v = *(const float4*)(Kb + (size_t)(s0 + s) * HDIM + hq);
        t[s][hq + 0] = v.x; t[s][hq + 1] = v.y; t[s][hq + 2] = v.z; t[s][hq + 3] = v.w;
    }
    __syncthreads();
    float* Ktb = Kt + (size_t)bh * HDIM * S_LEN;
#pragma unroll
    for (int i = 0; i < 4; ++i) {
        const int f = tid + i * 256;
        const int hd = f >> 4;
        const int sq = (f & 15) * 4;
        float4 v;
        v.x = t[sq + 0][hd]; v.y = t[sq + 1][hd];
        v.z = t[sq + 2][hd]; v.w = t[sq + 3][hd];
        *(float4*)(Ktb + (size_t)hd * S_LEN + s0 + sq) = v;
    }
}

// ---------------------------------------------------------------------------
// Fused attention: per block = one (b,h) and 4 query rows.
// scores (fp32, LDS) -> exact radix-select of 409th-largest -> softmax over
// kept set -> compacted PV -> AO[b,s,h*64+hd]
// ---------------------------------------------------------------------------
__global__ __launch_bounds__(256)
void attn_kernel(const float* __restrict__ Q, const float* __restrict__ Kt,
                 const float* __restrict__ V, float* __restrict__ AO)
{
    __shared__ __align__(16) float sc[4][2048];   // 32 KB
    __shared__ float qs[4][64];
    __shared__ int hist[4][256];
    __shared__ unsigned short idxl[4][1024];
    __shared__ int sel_d[4], sel_rem[4], kcount[4];

    const int tid = threadIdx.x;
    const int lane = tid & 63;
    const int w = tid >> 6;            // wave id == local q row

    // XCD swizzle: 8 XCDs x 4 heads each -> per-XCD K/V working set ~4MB (L2)
    const int blk = blockIdx.x;
    const int xcd = blk & 7;
    const int idx = blk >> 3;              // 0..2047
    const int bh  = xcd * 4 + (idx & 3);   // 0..31
    const int q0  = (idx >> 2) * 4;        // 0..2044

    {   // load 4 Q rows
        const int r = tid >> 6, d = tid & 63;
        qs[r][d] = Q[((size_t)bh * S_LEN + q0 + r) * HDIM + d];
    }
    if (tid < 4) kcount[tid] = 0;
    __syncthreads();

    const int r = w;

    // ---- scores: sc[r][j] = (q_r . k_j) / 8 ----
    const float* Ktb = Kt + (size_t)bh * HDIM * S_LEN;
    for (int jb = 0; jb < 8; ++jb) {
        const int j0 = jb * 256 + lane * 4;
        float ax = 0.f, ay = 0.f, az = 0.f, aw = 0.f;
#pragma unroll 8
        for (int d = 0; d < 64; ++d) {
            const float qv = qs[r][d];
            const float4 kv = *(const float4*)(Ktb + (size_t)d * S_LEN + j0);
            ax += qv * kv.x; ay += qv * kv.y; az += qv * kv.z; aw += qv * kv.w;
        }
        float4 o;
        o.x = ax * 0.125f; o.y = ay * 0.125f; o.z = az * 0.125f; o.w = aw * 0.125f;
        *(float4*)&sc[r][j0] = o;
    }
    __syncthreads();

    // ---- exact 409th-largest via 4-pass radix select on ordered uint ----
    unsigned pref = 0;
    int remaining = KK;
    for (int pass = 0; pass < 4; ++pass) {
        const int shift = 24 - 8 * pass;
#pragma unroll
        for (int i = 0; i < 4; ++i) hist[w][lane * 4 + i] = 0;
        __syncthreads();
        for (int i = 0; i < 32; ++i) {
            const unsigned u = f2ord(sc[r][i * 64 + lane]);
            const bool match = (pass == 0) || ((u >> (shift + 8)) == pref);
            if (match) atomicAdd(&hist[r][(u >> shift) & 255], 1);
        }
        __syncthreads();
        const int c0 = hist[r][lane * 4 + 0], c1 = hist[r][lane * 4 + 1];
        const int c2 = hist[r][lane * 4 + 2], c3 = hist[r][lane * 4 + 3];
        const int tot = c0 + c1 + c2 + c3;
        int suf = tot;
#pragma unroll
        for (int off = 1; off < 64; off <<= 1) {
            const int o = __shfl_down(suf, off);
            if (lane + off < 64) suf += o;
        }
        const int above3 = suf - tot;       // count of elements in higher bins
        const int above2 = above3 + c3;
        const int above1 = above2 + c2;
        const int above0 = above1 + c1;
        if (above3 < remaining && remaining <= above3 + c3) { sel_d[r] = lane * 4 + 3; sel_rem[r] = remaining - above3; }
        if (above2 < remaining && remaining <= above2 + c2) { sel_d[r] = lane * 4 + 2; sel_rem[r] = remaining - above2; }
        if (above1 < remaining && remaining <= above1 + c1) { sel_d[r] = lane * 4 + 1; sel_rem[r] = remaining - above1; }
        if (above0 < remaining && remaining <= above0 + c0) { sel_d[r] = lane * 4 + 0; sel_rem[r] = remaining - above0; }
        __syncthreads();
        pref = (pref << 8) | (unsigned)sel_d[r];
        remaining = sel_rem[r];
        __syncthreads();
    }
    const unsigned T = pref;   // bit pattern of the 409th largest score

    // ---- row max (max is always kept: max >= T) ----
    float mx = -1e30f;
    for (int i = 0; i < 32; ++i) mx = fmaxf(mx, sc[r][i * 64 + lane]);
#pragma unroll
    for (int off = 32; off >= 1; off >>= 1) mx = fmaxf(mx, __shfl_xor(mx, off));

    // ---- exp over kept set + compact index list ----
    float lsum = 0.f;
    for (int i = 0; i < 32; ++i) {
        const int j = i * 64 + lane;
        const float s = sc[r][j];
        float e = 0.f;
        if (f2ord(s) >= T) {
            e = __expf(s - mx);
            const int slot = atomicAdd(&kcount[r], 1);
            if (slot < 1024) idxl[r][slot] = (unsigned short)j;
        }
        sc[r][j] = e;
        lsum += e;
    }
#pragma unroll
    for (int off = 32; off >= 1; off >>= 1) lsum += __shfl_xor(lsum, off);
    const float invd = 1.f / lsum;
    __syncthreads();

    // ---- PV: out[r, 0..63] = sum_j p_j * V[j, :] ----
    const int kept = kcount[r];
    const int p  = (lane >> 4) & 3;   // 4 j-partitions per wave
    const int dq = lane & 15;         // 16 d-quads
    const float* Vb = V + (size_t)bh * S_LEN * HDIM;
    float ox = 0.f, oy = 0.f, oz = 0.f, ow = 0.f;
    if (kept <= 1024) {
        for (int t = p; t < kept; t += 4) {
            const int j = idxl[r][t];
            const float sp = sc[r][j];
            const float4 vv = *(const float4*)(Vb + (size_t)j * HDIM + dq * 4);
            ox += sp * vv.x; oy += sp * vv.y; oz += sp * vv.z; ow += sp * vv.w;
        }
    } else {   // pathological tie overflow: dense fallback (correct, slow)
        for (int j = p * 512; j < p * 512 + 512; ++j) {
            const float sp = sc[r][j];
            if (sp != 0.f) {
                const float4 vv = *(const float4*)(Vb + (size_t)j * HDIM + dq * 4);
                ox += sp * vv.x; oy += sp * vv.y; oz += sp * vv.z; ow += sp * vv.w;
            }
        }
    }
#pragma unroll
    for (int off = 16; off <= 32; off <<= 1) {   // reduce the 4 partitions
        ox += __shfl_xor(ox, off);
        oy += __shfl_xor(oy, off);
        oz += __shfl_xor(oz, off);
        ow += __shfl_xor(ow, off);
    }
    if (lane < 16) {
        const int b = bh >> 4, h = bh & 15;
        float4 o;
        o.x = ox * invd; o.y = oy * invd; o.z = oz * invd; o.w = ow * invd;
        *(float4*)(AO + ((size_t)(b * S_LEN + q0 + r)) * DMODEL + h * HDIM + dq * 4) = o;
    }
}

// ---------------------------------------------------------------------------
extern "C" void kernel_launch(void* const* d_in, const int* in_sizes, int n_in,
                              void* d_out, int out_size, void* d_ws, size_t ws_size,
                              hipStream_t stream)
{
    const float* X  = (const float*)d_in[0];
    const float* Wq = (const float*)d_in[1];
    const float* bq = (const float*)d_in[2];
    const float* Wk = (const float*)d_in[3];
    const float* bk = (const float*)d_in[4];
    const float* Wv = (const float*)d_in[5];
    const float* bv = (const float*)d_in[6];
    const float* Wo = (const float*)d_in[7];
    const float* bo = (const float*)d_in[8];

    float* ws = (float*)d_ws;
    const size_t SEG = (size_t)BHC * S_LEN * HDIM;  // 4,194,304 floats = 16 MB
    float* Qb  = ws;
    float* Kb  = ws + SEG;
    float* Ktb = ws + 2 * SEG;
    float* Vb  = ws + 3 * SEG;
    float* AO  = ws + 4 * SEG;   // [B,S,D]

    const dim3 ggrid(16, 32, 1);
    gemm_nt<<<ggrid, 256, 0, stream>>>(X, Wq, bq, Qb, 1);
    gemm_nt<<<ggrid, 256, 0, stream>>>(X, Wk, bk, Kb, 1);
    gemm_nt<<<ggrid, 256, 0, stream>>>(X, Wv, bv, Vb, 1);
    transpose_k<<<dim3(32, 32, 1), 256, 0, stream>>>(Kb, Ktb);
    attn_kernel<<<16384, 256, 0, stream>>>(Qb, Ktb, Vb, AO);
    gemm_nt<<<ggrid, 256, 0, stream>>>(AO, Wo, bo, (float*)d_out, 0);
}